// Round 1
// baseline (192.684 us; speedup 1.0000x reference)
//
#include <hip/hip_runtime.h>

typedef short short8 __attribute__((ext_vector_type(8)));
typedef float f32x4 __attribute__((ext_vector_type(4)));

#define NB 16
#define H 128
#define TSTEPS 64
#define PRED 32
#define XROWSTRIDE 260  // 64*4 + 4 pad floats -> conflict-free broadcast reads

__device__ __forceinline__ unsigned short bf16_rne(float f) {
  unsigned u = __builtin_bit_cast(unsigned, f);
  u += 0x7fffu + ((u >> 16) & 1u);
  return (unsigned short)(u >> 16);
}
__device__ __forceinline__ float bf16_f(unsigned short s) {
  unsigned u = ((unsigned)s) << 16;
  return __builtin_bit_cast(float, u);
}
__device__ __forceinline__ float tanh_fast(float v) {
  v = fminf(9.0f, fmaxf(-9.0f, v));
  float e = __expf(2.0f * v);
  return __fdividef(e - 1.0f, e + 1.0f);
}

__global__ __launch_bounds__(256, 1) void traj_kernel(
    const float* __restrict__ x,
    const float* __restrict__ eWih, const float* __restrict__ eWhh,
    const float* __restrict__ ebih, const float* __restrict__ ebhh,
    const float* __restrict__ dWih, const float* __restrict__ dWhh,
    const float* __restrict__ dbih, const float* __restrict__ dbhh,
    const float* __restrict__ fcW, const float* __restrict__ fcb,
    float* __restrict__ out)
{
  __shared__ __align__(16) float x_lds[NB * XROWSTRIDE];   // 16.6 KB
  __shared__ __align__(16) short h_hi[2][NB * H];          // 8 KB  (XOR-swizzled)
  __shared__ __align__(16) short h_lo[2][NB * H];          // 8 KB
  __shared__ float inp_lds[NB][4];
  __shared__ float part[4][NB][3];

  const int tid = threadIdx.x;
  const int lane = tid & 63;
  const int wave = tid >> 6;
  const int l4 = lane >> 4;
  const int ln = lane & 15;
  const int r0 = blockIdx.x * NB;

  // ---- stage x tile (16 rows x 64 t x 3) into padded LDS ----
  #pragma unroll
  for (int s = 0; s < 12; ++s) {
    int flat = tid + s * 256;        // = r*192 + rem
    int r = flat / 192;
    int rem = flat - r * 192;
    int t = rem / 3;
    int i = rem - t * 3;
    x_lds[r * XROWSTRIDE + t * 4 + i] = x[(size_t)r0 * 192 + flat];
  }
  // ---- zero h buffer 0 (h0 = 0) ----
  #pragma unroll
  for (int s = 0; s < 8; ++s) {
    h_hi[0][tid + s * 256] = 0;
    h_lo[0][tid + s * 256] = 0;
  }

  const int jj0 = wave * 32 + ln;   // this lane's two hidden columns
  const int jj1 = jj0 + 16;

  // ---- encoder weight fragments (B operand = Whh^T), split hi/lo, in VGPRs ----
  short8 whi[2][4], wlo[2][4];
  #pragma unroll
  for (int ct = 0; ct < 2; ++ct) {
    const int j = ct ? jj1 : jj0;
    #pragma unroll
    for (int kt = 0; kt < 4; ++kt) {
      const float* p = eWhh + j * H + kt * 32 + l4 * 8;
      f32x4 a = *(const f32x4*)p;
      f32x4 b = *(const f32x4*)(p + 4);
      short8 hi, lo;
      #pragma unroll
      for (int e = 0; e < 4; ++e) {
        unsigned short h1 = bf16_rne(a[e]);
        hi[e] = (short)h1;
        lo[e] = (short)bf16_rne(a[e] - bf16_f(h1));
        unsigned short h2 = bf16_rne(b[e]);
        hi[e + 4] = (short)h2;
        lo[e + 4] = (short)bf16_rne(b[e] - bf16_f(h2));
      }
      whi[ct][kt] = hi;
      wlo[ct][kt] = lo;
    }
  }
  float bias0 = ebih[jj0] + ebhh[jj0];
  float bias1 = ebih[jj1] + ebhh[jj1];
  float wi0[3], wi1[3];
  #pragma unroll
  for (int i = 0; i < 3; ++i) { wi0[i] = eWih[jj0 * 3 + i]; wi1[i] = eWih[jj1 * 3 + i]; }

  __syncthreads();

  int cur = 0;
  // ======================= encoder: 64 steps, 1 barrier/step =======================
  for (int t = 0; t < TSTEPS; ++t) {
    short8 ah[4], al[4];
    #pragma unroll
    for (int kt = 0; kt < 4; ++kt) {
      const int idx = ln * H + ((((kt << 2) + l4) ^ ln) << 3);   // swizzled A-frag
      ah[kt] = *(const short8*)&h_hi[cur][idx];
      al[kt] = *(const short8*)&h_lo[cur][idx];
    }
    f32x4 acc0, acc1, acc0b, acc1b, acc0c, acc1c;
    #pragma unroll
    for (int reg = 0; reg < 4; ++reg) {
      const int r = l4 * 4 + reg;
      const f32x4 xv = *(const f32x4*)&x_lds[r * XROWSTRIDE + t * 4];
      acc0[reg] = bias0 + wi0[0] * xv[0] + wi0[1] * xv[1] + wi0[2] * xv[2];
      acc1[reg] = bias1 + wi1[0] * xv[0] + wi1[1] * xv[1] + wi1[2] * xv[2];
      acc0b[reg] = 0.f; acc1b[reg] = 0.f; acc0c[reg] = 0.f; acc1c[reg] = 0.f;
    }
    #pragma unroll
    for (int kt = 0; kt < 4; ++kt) {   // 6 independent 4-deep MFMA chains
      acc0  = __builtin_amdgcn_mfma_f32_16x16x32_bf16(ah[kt], whi[0][kt], acc0, 0, 0, 0);
      acc1  = __builtin_amdgcn_mfma_f32_16x16x32_bf16(ah[kt], whi[1][kt], acc1, 0, 0, 0);
      acc0b = __builtin_amdgcn_mfma_f32_16x16x32_bf16(ah[kt], wlo[0][kt], acc0b, 0, 0, 0);
      acc1b = __builtin_amdgcn_mfma_f32_16x16x32_bf16(ah[kt], wlo[1][kt], acc1b, 0, 0, 0);
      acc0c = __builtin_amdgcn_mfma_f32_16x16x32_bf16(al[kt], whi[0][kt], acc0c, 0, 0, 0);
      acc1c = __builtin_amdgcn_mfma_f32_16x16x32_bf16(al[kt], whi[1][kt], acc1c, 0, 0, 0);
    }
    const int nxt = cur ^ 1;
    #pragma unroll
    for (int reg = 0; reg < 4; ++reg) {
      const int r = l4 * 4 + reg;
      float v0 = tanh_fast(acc0[reg] + acc0b[reg] + acc0c[reg]);
      float v1 = tanh_fast(acc1[reg] + acc1b[reg] + acc1c[reg]);
      unsigned short p0 = bf16_rne(v0);
      unsigned short p1 = bf16_rne(v1);
      const int idx0 = r * H + (((jj0 >> 3) ^ r) << 3) + (jj0 & 7);
      const int idx1 = r * H + (((jj1 >> 3) ^ r) << 3) + (jj1 & 7);
      h_hi[nxt][idx0] = (short)p0;
      h_hi[nxt][idx1] = (short)p1;
      h_lo[nxt][idx0] = (short)bf16_rne(v0 - bf16_f(p0));
      h_lo[nxt][idx1] = (short)bf16_rne(v1 - bf16_f(p1));
    }
    cur = nxt;
    __syncthreads();
  }

  // ======================= decoder setup =======================
  #pragma unroll
  for (int ct = 0; ct < 2; ++ct) {
    const int j = ct ? jj1 : jj0;
    #pragma unroll
    for (int kt = 0; kt < 4; ++kt) {
      const float* p = dWhh + j * H + kt * 32 + l4 * 8;
      f32x4 a = *(const f32x4*)p;
      f32x4 b = *(const f32x4*)(p + 4);
      short8 hi, lo;
      #pragma unroll
      for (int e = 0; e < 4; ++e) {
        unsigned short h1 = bf16_rne(a[e]);
        hi[e] = (short)h1;
        lo[e] = (short)bf16_rne(a[e] - bf16_f(h1));
        unsigned short h2 = bf16_rne(b[e]);
        hi[e + 4] = (short)h2;
        lo[e + 4] = (short)bf16_rne(b[e] - bf16_f(h2));
      }
      whi[ct][kt] = hi;
      wlo[ct][kt] = lo;
    }
  }
  bias0 = dbih[jj0] + dbhh[jj0];
  bias1 = dbih[jj1] + dbhh[jj1];
  #pragma unroll
  for (int i = 0; i < 3; ++i) { wi0[i] = dWih[jj0 * 3 + i]; wi1[i] = dWih[jj1 * 3 + i]; }
  float fw0[3], fw1[3];
  #pragma unroll
  for (int o = 0; o < 3; ++o) { fw0[o] = fcW[o * H + jj0]; fw1[o] = fcW[o * H + jj1]; }
  if (tid < 48) {
    int r = tid / 3, i = tid - 3 * (tid / 3);
    inp_lds[r][i] = x_lds[r * XROWSTRIDE + 63 * 4 + i];   // dec_in0 = x[:, -1, :]
  }
  __syncthreads();

  // ======================= decoder: 32 steps =======================
  for (int s = 0; s < PRED; ++s) {
    short8 ah[4], al[4];
    #pragma unroll
    for (int kt = 0; kt < 4; ++kt) {
      const int idx = ln * H + ((((kt << 2) + l4) ^ ln) << 3);
      ah[kt] = *(const short8*)&h_hi[cur][idx];
      al[kt] = *(const short8*)&h_lo[cur][idx];
    }
    f32x4 acc0, acc1, acc0b, acc1b, acc0c, acc1c;
    #pragma unroll
    for (int reg = 0; reg < 4; ++reg) {
      const int r = l4 * 4 + reg;
      float i0 = inp_lds[r][0], i1 = inp_lds[r][1], i2 = inp_lds[r][2];
      acc0[reg] = bias0 + wi0[0] * i0 + wi0[1] * i1 + wi0[2] * i2;
      acc1[reg] = bias1 + wi1[0] * i0 + wi1[1] * i1 + wi1[2] * i2;
      acc0b[reg] = 0.f; acc1b[reg] = 0.f; acc0c[reg] = 0.f; acc1c[reg] = 0.f;
    }
    #pragma unroll
    for (int kt = 0; kt < 4; ++kt) {
      acc0  = __builtin_amdgcn_mfma_f32_16x16x32_bf16(ah[kt], whi[0][kt], acc0, 0, 0, 0);
      acc1  = __builtin_amdgcn_mfma_f32_16x16x32_bf16(ah[kt], whi[1][kt], acc1, 0, 0, 0);
      acc0b = __builtin_amdgcn_mfma_f32_16x16x32_bf16(ah[kt], wlo[0][kt], acc0b, 0, 0, 0);
      acc1b = __builtin_amdgcn_mfma_f32_16x16x32_bf16(ah[kt], wlo[1][kt], acc1b, 0, 0, 0);
      acc0c = __builtin_amdgcn_mfma_f32_16x16x32_bf16(al[kt], whi[0][kt], acc0c, 0, 0, 0);
      acc1c = __builtin_amdgcn_mfma_f32_16x16x32_bf16(al[kt], whi[1][kt], acc1c, 0, 0, 0);
    }
    const int nxt = cur ^ 1;
    float hv0[4], hv1[4];
    #pragma unroll
    for (int reg = 0; reg < 4; ++reg) {
      const int r = l4 * 4 + reg;
      float v0 = tanh_fast(acc0[reg] + acc0b[reg] + acc0c[reg]);
      float v1 = tanh_fast(acc1[reg] + acc1b[reg] + acc1c[reg]);
      hv0[reg] = v0; hv1[reg] = v1;
      unsigned short p0 = bf16_rne(v0);
      unsigned short p1 = bf16_rne(v1);
      const int idx0 = r * H + (((jj0 >> 3) ^ r) << 3) + (jj0 & 7);
      const int idx1 = r * H + (((jj1 >> 3) ^ r) << 3) + (jj1 & 7);
      h_hi[nxt][idx0] = (short)p0;
      h_hi[nxt][idx1] = (short)p1;
      h_lo[nxt][idx0] = (short)bf16_rne(v0 - bf16_f(p0));
      h_lo[nxt][idx1] = (short)bf16_rne(v1 - bf16_f(p1));
    }
    // fc head partials: this lane covers hidden cols jj0, jj1 for 4 rows
    float pp[4][3];
    #pragma unroll
    for (int reg = 0; reg < 4; ++reg)
      #pragma unroll
      for (int o = 0; o < 3; ++o)
        pp[reg][o] = fw0[o] * hv0[reg] + fw1[o] * hv1[reg];
    #pragma unroll
    for (int m = 1; m <= 8; m <<= 1) {
      #pragma unroll
      for (int reg = 0; reg < 4; ++reg)
        #pragma unroll
        for (int o = 0; o < 3; ++o)
          pp[reg][o] += __shfl_xor(pp[reg][o], m, 64);
    }
    if (ln == 0) {
      #pragma unroll
      for (int reg = 0; reg < 4; ++reg)
        #pragma unroll
        for (int o = 0; o < 3; ++o)
          part[wave][l4 * 4 + reg][o] = pp[reg][o];
    }
    cur = nxt;
    __syncthreads();
    if (tid < 48) {
      int r = tid / 3, o = tid - 3 * (tid / 3);
      float pr = fcb[o] + part[0][r][o] + part[1][r][o] + part[2][r][o] + part[3][r][o];
      out[((size_t)(r0 + r) * PRED + s) * 3 + o] = pr;
      inp_lds[r][o] = pr;   // feedback: next decoder input
    }
    __syncthreads();
  }
}

extern "C" void kernel_launch(void* const* d_in, const int* in_sizes, int n_in,
                              void* d_out, int out_size, void* d_ws, size_t ws_size,
                              hipStream_t stream) {
  (void)in_sizes; (void)n_in; (void)out_size; (void)d_ws; (void)ws_size;
  const float* x    = (const float*)d_in[0];
  const float* eWih = (const float*)d_in[1];
  const float* eWhh = (const float*)d_in[2];
  const float* ebih = (const float*)d_in[3];
  const float* ebhh = (const float*)d_in[4];
  const float* dWih = (const float*)d_in[5];
  const float* dWhh = (const float*)d_in[6];
  const float* dbih = (const float*)d_in[7];
  const float* dbhh = (const float*)d_in[8];
  const float* fcW  = (const float*)d_in[9];
  const float* fcb  = (const float*)d_in[10];
  float* out = (float*)d_out;
  traj_kernel<<<dim3(256), dim3(256), 0, stream>>>(
      x, eWih, eWhh, ebih, ebhh, dWih, dWhh, dbih, dbhh, fcW, fcb, out);
}

// Round 2
// 183.455 us; speedup vs baseline: 1.0503x; 1.0503x over previous
//
#include <hip/hip_runtime.h>

typedef short short8 __attribute__((ext_vector_type(8)));
typedef float f32x4 __attribute__((ext_vector_type(4)));

#define NB 16
#define H 128
#define TSTEPS 64
#define PRED 32
#define XROWSTRIDE 260  // 64*4 + 4 pad floats -> conflict-free broadcast reads
#define NWAVE 8

__device__ __forceinline__ unsigned short bf16_rne(float f) {
  unsigned u = __builtin_bit_cast(unsigned, f);
  u += 0x7fffu + ((u >> 16) & 1u);
  return (unsigned short)(u >> 16);
}
__device__ __forceinline__ float bf16_f(unsigned short s) {
  unsigned u = ((unsigned)s) << 16;
  return __builtin_bit_cast(float, u);
}
__device__ __forceinline__ float tanh_fast(float v) {
  v = fminf(9.0f, fmaxf(-9.0f, v));
  float e = __expf(2.0f * v);
  return __fdividef(e - 1.0f, e + 1.0f);
}

// Split an 8-float chunk (two f32x4) into bf16 hi/lo fragments.
__device__ __forceinline__ void split_frag(const f32x4& a, const f32x4& b,
                                           short8& hi, short8& lo) {
  #pragma unroll
  for (int e = 0; e < 4; ++e) {
    unsigned short h1 = bf16_rne(a[e]);
    hi[e] = (short)h1;
    lo[e] = (short)bf16_rne(a[e] - bf16_f(h1));
    unsigned short h2 = bf16_rne(b[e]);
    hi[e + 4] = (short)h2;
    lo[e + 4] = (short)bf16_rne(b[e] - bf16_f(h2));
  }
}

// One RNN step for this wave's 16-col tile. acc0 comes in pre-initialized with
// bias + input term. Reads h(cur) from LDS (swizzled), writes h(nxt), returns
// post-tanh values in hv[4].
__device__ __forceinline__ void rnn_step(
    const short* __restrict__ hc_hi, const short* __restrict__ hc_lo,
    short* __restrict__ hn_hi, short* __restrict__ hn_lo,
    const short8 whi[4], const short8 wlo[4],
    f32x4 acc0, int l4, int ln, int jj, float hv[4]) {
  short8 ah[4], al[4];
  #pragma unroll
  for (int kt = 0; kt < 4; ++kt) {
    const int idx = ln * H + ((((kt << 2) + l4) ^ ln) << 3);  // swizzled A-frag
    ah[kt] = *(const short8*)&hc_hi[idx];
    al[kt] = *(const short8*)&hc_lo[idx];
  }
  f32x4 accb = {0.f, 0.f, 0.f, 0.f};
  f32x4 accc = {0.f, 0.f, 0.f, 0.f};
  #pragma unroll
  for (int kt = 0; kt < 4; ++kt) {  // 3 independent 4-deep MFMA chains
    acc0 = __builtin_amdgcn_mfma_f32_16x16x32_bf16(ah[kt], whi[kt], acc0, 0, 0, 0);
    accb = __builtin_amdgcn_mfma_f32_16x16x32_bf16(ah[kt], wlo[kt], accb, 0, 0, 0);
    accc = __builtin_amdgcn_mfma_f32_16x16x32_bf16(al[kt], whi[kt], accc, 0, 0, 0);
  }
  #pragma unroll
  for (int reg = 0; reg < 4; ++reg) {
    const int r = l4 * 4 + reg;
    float v = tanh_fast(acc0[reg] + accb[reg] + accc[reg]);
    hv[reg] = v;
    unsigned short p = bf16_rne(v);
    const int idx = r * H + (((jj >> 3) ^ r) << 3) + (jj & 7);
    hn_hi[idx] = (short)p;
    hn_lo[idx] = (short)bf16_rne(v - bf16_f(p));
  }
}

__global__ __launch_bounds__(512, 2) void traj_kernel(
    const float* __restrict__ x,
    const float* __restrict__ eWih, const float* __restrict__ eWhh,
    const float* __restrict__ ebih, const float* __restrict__ ebhh,
    const float* __restrict__ dWih, const float* __restrict__ dWhh,
    const float* __restrict__ dbih, const float* __restrict__ dbhh,
    const float* __restrict__ fcW, const float* __restrict__ fcb,
    float* __restrict__ out)
{
  __shared__ __align__(16) float x_lds[NB * XROWSTRIDE];   // 16.6 KB
  __shared__ __align__(16) short h_hi[2][NB * H];          // 8 KB (XOR-swizzled)
  __shared__ __align__(16) short h_lo[2][NB * H];          // 8 KB
  __shared__ float inp_lds[NB][4];
  __shared__ float part[2][NWAVE][NB][3];                  // 3 KB, dbuf'd

  const int tid = threadIdx.x;
  const int lane = tid & 63;
  const int w = tid >> 6;          // wave 0..7 -> 16-col tile
  const int l4 = lane >> 4;
  const int ln = lane & 15;
  const int r0 = blockIdx.x * NB;
  const int jj = w * 16 + ln;      // this lane's hidden column

  // ---- stage x tile (16 rows x 64 t x 3) into padded LDS ----
  #pragma unroll
  for (int s = 0; s < 6; ++s) {
    int flat = tid + s * 512;      // = r*192 + rem
    int r = flat / 192;
    int rem = flat - r * 192;
    int t = rem / 3;
    int i = rem - t * 3;
    x_lds[r * XROWSTRIDE + t * 4 + i] = x[(size_t)r0 * 192 + flat];
  }
  // ---- zero h buffer 0 (h0 = 0) ----
  #pragma unroll
  for (int s = 0; s < 4; ++s) {
    h_hi[0][tid + s * 512] = 0;
    h_lo[0][tid + s * 512] = 0;
  }

  // ---- encoder weight fragments (row jj of eWhh), split hi/lo ----
  short8 whi[4], wlo[4];
  #pragma unroll
  for (int kt = 0; kt < 4; ++kt) {
    const float* p = eWhh + jj * H + kt * 32 + l4 * 8;
    split_frag(*(const f32x4*)p, *(const f32x4*)(p + 4), whi[kt], wlo[kt]);
  }
  float bias = ebih[jj] + ebhh[jj];
  float wi[3];
  #pragma unroll
  for (int i = 0; i < 3; ++i) wi[i] = eWih[jj * 3 + i];

  __syncthreads();

  int cur = 0;
  float hv[4];
  // ======================= encoder: 64 steps, 1 barrier/step =======================
  for (int t = 0; t < TSTEPS; ++t) {
    f32x4 acc0;
    #pragma unroll
    for (int reg = 0; reg < 4; ++reg) {
      const int r = l4 * 4 + reg;
      const f32x4 xv = *(const f32x4*)&x_lds[r * XROWSTRIDE + t * 4];
      acc0[reg] = bias + wi[0] * xv[0] + wi[1] * xv[1] + wi[2] * xv[2];
    }
    const int nxt = cur ^ 1;
    rnn_step(h_hi[cur], h_lo[cur], h_hi[nxt], h_lo[nxt], whi, wlo,
             acc0, l4, ln, jj, hv);
    cur = nxt;
    __syncthreads();
  }

  // ======================= decoder setup (step 0 uses raw dWhh) =======================
  #pragma unroll
  for (int kt = 0; kt < 4; ++kt) {
    const float* p = dWhh + jj * H + kt * 32 + l4 * 8;
    split_frag(*(const f32x4*)p, *(const f32x4*)(p + 4), whi[kt], wlo[kt]);
  }
  bias = dbih[jj] + dbhh[jj];
  #pragma unroll
  for (int i = 0; i < 3; ++i) wi[i] = dWih[jj * 3 + i];
  float fw[3];
  #pragma unroll
  for (int o = 0; o < 3; ++o) fw[o] = fcW[o * H + jj];
  if (tid < 48) {
    int r = tid / 3, i = tid - 3 * (tid / 3);
    inp_lds[r][i] = x_lds[r * XROWSTRIDE + 63 * 4 + i];   // dec_in0 = x[:, -1, :]
  }
  __syncthreads();

  // ---- decoder step 0 ----
  {
    f32x4 acc0;
    #pragma unroll
    for (int reg = 0; reg < 4; ++reg) {
      const int r = l4 * 4 + reg;
      acc0[reg] = bias + wi[0] * inp_lds[r][0] + wi[1] * inp_lds[r][1]
                       + wi[2] * inp_lds[r][2];
    }
    const int nxt = cur ^ 1;
    rnn_step(h_hi[cur], h_lo[cur], h_hi[nxt], h_lo[nxt], whi, wlo,
             acc0, l4, ln, jj, hv);
    // fc head partials (off the recurrence critical path)
    float pp[4][3];
    #pragma unroll
    for (int reg = 0; reg < 4; ++reg)
      #pragma unroll
      for (int o = 0; o < 3; ++o)
        pp[reg][o] = fw[o] * hv[reg];
    #pragma unroll
    for (int m = 1; m <= 8; m <<= 1)
      #pragma unroll
      for (int reg = 0; reg < 4; ++reg)
        #pragma unroll
        for (int o = 0; o < 3; ++o)
          pp[reg][o] += __shfl_xor(pp[reg][o], m, 64);
    if (ln == 0)
      #pragma unroll
      for (int reg = 0; reg < 4; ++reg)
        #pragma unroll
        for (int o = 0; o < 3; ++o)
          part[0][w][l4 * 4 + reg][o] = pp[reg][o];
    cur = nxt;
    __syncthreads();
    if (tid < 48) {
      int r = tid / 3, o = tid - 3 * (tid / 3);
      float pr = fcb[o];
      #pragma unroll
      for (int ww = 0; ww < NWAVE; ++ww) pr += part[0][ww][r][o];
      out[((size_t)(r0 + r) * PRED + 0) * 3 + o] = pr;
    }
  }

  // ---- build combined weights W' = dWhh + dWih@fcW ; bias' = db + dWih@fcb ----
  #pragma unroll
  for (int kt = 0; kt < 4; ++kt) {
    const int kb = kt * 32 + l4 * 8;
    f32x4 a = *(const f32x4*)(dWhh + jj * H + kb);
    f32x4 b = *(const f32x4*)(dWhh + jj * H + kb + 4);
    #pragma unroll
    for (int o = 0; o < 3; ++o) {
      const f32x4 fa = *(const f32x4*)(fcW + o * H + kb);
      const f32x4 fb = *(const f32x4*)(fcW + o * H + kb + 4);
      #pragma unroll
      for (int e = 0; e < 4; ++e) {
        a[e] += wi[o] * fa[e];
        b[e] += wi[o] * fb[e];
      }
    }
    split_frag(a, b, whi[kt], wlo[kt]);
  }
  float biasp = bias + wi[0] * fcb[0] + wi[1] * fcb[1] + wi[2] * fcb[2];

  // ======================= decoder steps 1..31: pure RNN, constant input =======================
  for (int s = 1; s < PRED; ++s) {
    f32x4 acc0 = {biasp, biasp, biasp, biasp};
    const int nxt = cur ^ 1;
    rnn_step(h_hi[cur], h_lo[cur], h_hi[nxt], h_lo[nxt], whi, wlo,
             acc0, l4, ln, jj, hv);
    float pp[4][3];
    #pragma unroll
    for (int reg = 0; reg < 4; ++reg)
      #pragma unroll
      for (int o = 0; o < 3; ++o)
        pp[reg][o] = fw[o] * hv[reg];
    #pragma unroll
    for (int m = 1; m <= 8; m <<= 1)
      #pragma unroll
      for (int reg = 0; reg < 4; ++reg)
        #pragma unroll
        for (int o = 0; o < 3; ++o)
          pp[reg][o] += __shfl_xor(pp[reg][o], m, 64);
    if (ln == 0)
      #pragma unroll
      for (int reg = 0; reg < 4; ++reg)
        #pragma unroll
        for (int o = 0; o < 3; ++o)
          part[s & 1][w][l4 * 4 + reg][o] = pp[reg][o];
    cur = nxt;
    __syncthreads();
    if (tid < 48) {
      int r = tid / 3, o = tid - 3 * (tid / 3);
      float pr = fcb[o];
      #pragma unroll
      for (int ww = 0; ww < NWAVE; ++ww) pr += part[s & 1][ww][r][o];
      out[((size_t)(r0 + r) * PRED + s) * 3 + o] = pr;
    }
  }
}

extern "C" void kernel_launch(void* const* d_in, const int* in_sizes, int n_in,
                              void* d_out, int out_size, void* d_ws, size_t ws_size,
                              hipStream_t stream) {
  (void)in_sizes; (void)n_in; (void)out_size; (void)d_ws; (void)ws_size;
  const float* x    = (const float*)d_in[0];
  const float* eWih = (const float*)d_in[1];
  const float* eWhh = (const float*)d_in[2];
  const float* ebih = (const float*)d_in[3];
  const float* ebhh = (const float*)d_in[4];
  const float* dWih = (const float*)d_in[5];
  const float* dWhh = (const float*)d_in[6];
  const float* dbih = (const float*)d_in[7];
  const float* dbhh = (const float*)d_in[8];
  const float* fcW  = (const float*)d_in[9];
  const float* fcb  = (const float*)d_in[10];
  float* out = (float*)d_out;
  traj_kernel<<<dim3(256), dim3(512), 0, stream>>>(
      x, eWih, eWhh, ebih, ebhh, dWih, dWhh, dbih, dbhh, fcW, fcb, out);
}